// Round 1
// baseline (1788.872 us; speedup 1.0000x reference)
//
#include <hip/hip_runtime.h>

#define B_ 256
#define T_ 128
#define E_ 512
#define H_ 512
#define KK 1024   // E_ + H_
#define NG 2048   // 4*H_

typedef __attribute__((ext_vector_type(8))) short bf16x8;
typedef __attribute__((ext_vector_type(4))) float f32x4;

__device__ __forceinline__ short f2bf(float f) {
  union { float f; unsigned u; } x; x.f = f;
  unsigned r = x.u + 0x7FFFu + ((x.u >> 16) & 1u);  // RNE
  return (short)(r >> 16);
}
__device__ __forceinline__ float bf2f(short s) {
  union { unsigned u; float f; } x;
  x.u = ((unsigned)(unsigned short)s) << 16; return x.f;
}
__device__ __forceinline__ float sigm(float x) { return 1.0f / (1.0f + __expf(-x)); }

// ---- Wt[j][k] = bf16( k<512 ? Wx[k][j] : Uh[k-512][j] ), j in [0,2048), k in [0,1024)
__global__ __launch_bounds__(256) void prep_w(const float* __restrict__ Wx,
                                              const float* __restrict__ Uh,
                                              short* __restrict__ Wt) {
  __shared__ float tile[64][65];
  const int k0 = blockIdx.x * 64;   // 16 blocks
  const int j0 = blockIdx.y * 64;   // 32 blocks
  const int tx = threadIdx.x & 63, ty = threadIdx.x >> 6;  // ty 0..3
#pragma unroll
  for (int r = 0; r < 16; ++r) {
    int k = k0 + r * 4 + ty;
    float v = (k < 512) ? Wx[(size_t)k * NG + j0 + tx]
                        : Uh[(size_t)(k - 512) * NG + j0 + tx];
    tile[r * 4 + ty][tx] = v;
  }
  __syncthreads();
#pragma unroll
  for (int r = 0; r < 16; ++r) {
    int j = j0 + r * 4 + ty;
    Wt[(size_t)j * KK + k0 + tx] = f2bf(tile[tx][r * 4 + ty]);
  }
}

__global__ __launch_bounds__(256) void prep_b(const float* __restrict__ bx,
                                              const float* __restrict__ bu,
                                              float* __restrict__ bcat) {
  int i = blockIdx.x * 256 + threadIdx.x;
  bcat[i] = bx[i] + bu[i];
}

// ---- xs[t][b][e] = bf16(emb[captions[b][t]][e]), zero row for token 0 (padding_idx)
__global__ __launch_bounds__(256) void stage_x(const int* __restrict__ captions,
                                               const float* __restrict__ emb,
                                               short* __restrict__ xs) {
  const int bid = blockIdx.x;          // = t*B_ + b
  const int t = bid >> 8, b = bid & 255;
  const int tok = captions[b * T_ + t];
  short* o = xs + (size_t)bid * E_;
  const float* src = emb + (size_t)tok * E_;
  int e0 = threadIdx.x, e1 = threadIdx.x + 256;
  if (tok) { o[e0] = f2bf(src[e0]); o[e1] = f2bf(src[e1]); }
  else     { o[e0] = 0;             o[e1] = 0; }
}

// ---- one LSTM timestep: g = [x_t | h] @ Wcat + bcat; gate math; update c, h
// grid: (8 M-tiles of 32 rows, 32 hidden-tiles of 16). block: 256 = 4 waves, wave w = gate w.
__global__ __launch_bounds__(256) void lstm_step(
    const short* __restrict__ xs,       // staged x (bf16) or nullptr
    const int* __restrict__ captions,   // fallback gather
    const float* __restrict__ emb,      // fallback gather
    const short* __restrict__ Wt,       // [2048][1024] bf16
    const float* __restrict__ bcat,     // [2048]
    const short* __restrict__ h_in,     // [256][512] bf16
    short* __restrict__ h_out,          // [256][512] bf16
    float* __restrict__ c,              // [256][512] f32
    int t) {
  const int tid = threadIdx.x;
  const int wave = tid >> 6;            // gate index 0..3 (i,f,o,g)
  const int lane = tid & 63;
  const int l15 = lane & 15, l4 = lane >> 4;
  const int row0 = blockIdx.x * 32;
  const int h0 = blockIdx.y * 16;
  const int col0 = wave * 512 + h0;     // gate column in [0,2048)

  __shared__ float g_lds[4][32][16];

  f32x4 acc0 = {0.f, 0.f, 0.f, 0.f};
  f32x4 acc1 = {0.f, 0.f, 0.f, 0.f};

  const short* wptr = Wt + (size_t)(col0 + l15) * KK + l4 * 8;
  const int rA0 = row0 + l15, rA1 = rA0 + 16;

  // ---- K phase 1: x_t (k = 0..511)
  if (xs) {
    const short* xp0 = xs + ((size_t)t * B_ + rA0) * E_ + l4 * 8;
    const short* xp1 = xs + ((size_t)t * B_ + rA1) * E_ + l4 * 8;
#pragma unroll
    for (int ks = 0; ks < 16; ++ks) {
      bf16x8 bw = *(const bf16x8*)(wptr + ks * 32);
      bf16x8 a0 = *(const bf16x8*)(xp0 + ks * 32);
      bf16x8 a1 = *(const bf16x8*)(xp1 + ks * 32);
      acc0 = __builtin_amdgcn_mfma_f32_16x16x32_bf16(a0, bw, acc0, 0, 0, 0);
      acc1 = __builtin_amdgcn_mfma_f32_16x16x32_bf16(a1, bw, acc1, 0, 0, 0);
    }
  } else {
    const int tok0 = captions[rA0 * T_ + t];
    const int tok1 = captions[rA1 * T_ + t];
    const float* e0 = emb + (size_t)tok0 * E_ + l4 * 8;
    const float* e1 = emb + (size_t)tok1 * E_ + l4 * 8;
#pragma unroll
    for (int ks = 0; ks < 16; ++ks) {
      bf16x8 bw = *(const bf16x8*)(wptr + ks * 32);
      bf16x8 a0 = {}, a1 = {};
      if (tok0) {
#pragma unroll
        for (int i = 0; i < 8; ++i) a0[i] = f2bf(e0[ks * 32 + i]);
      }
      if (tok1) {
#pragma unroll
        for (int i = 0; i < 8; ++i) a1[i] = f2bf(e1[ks * 32 + i]);
      }
      acc0 = __builtin_amdgcn_mfma_f32_16x16x32_bf16(a0, bw, acc0, 0, 0, 0);
      acc1 = __builtin_amdgcn_mfma_f32_16x16x32_bf16(a1, bw, acc1, 0, 0, 0);
    }
  }

  // ---- K phase 2: h_{t-1} (k = 512..1023)
  {
    const short* hp0 = h_in + (size_t)rA0 * H_ + l4 * 8;
    const short* hp1 = h_in + (size_t)rA1 * H_ + l4 * 8;
#pragma unroll
    for (int ks = 0; ks < 16; ++ks) {
      bf16x8 bw = *(const bf16x8*)(wptr + (16 + ks) * 32);
      bf16x8 a0 = *(const bf16x8*)(hp0 + ks * 32);
      bf16x8 a1 = *(const bf16x8*)(hp1 + ks * 32);
      acc0 = __builtin_amdgcn_mfma_f32_16x16x32_bf16(a0, bw, acc0, 0, 0, 0);
      acc1 = __builtin_amdgcn_mfma_f32_16x16x32_bf16(a1, bw, acc1, 0, 0, 0);
    }
  }

  // C/D layout (m89-verified): col = lane&15, row = (lane>>4)*4 + reg
#pragma unroll
  for (int r = 0; r < 4; ++r) {
    g_lds[wave][l4 * 4 + r][l15] = acc0[r];
    g_lds[wave][16 + l4 * 4 + r][l15] = acc1[r];
  }
  __syncthreads();

  // ---- gates, elementwise over the 32x16 tile
#pragma unroll
  for (int idx = tid; idx < 512; idx += 256) {
    const int r = idx >> 4, j = idx & 15;
    const int R = row0 + r, J = h0 + j;
    float iv = g_lds[0][r][j] + bcat[J];
    float fv = g_lds[1][r][j] + bcat[512 + J];
    float ov = g_lds[2][r][j] + bcat[1024 + J];
    float gv = g_lds[3][r][j] + bcat[1536 + J];
    float co = c[(size_t)R * H_ + J];
    float cn = sigm(fv) * co + sigm(iv) * tanhf(gv);
    c[(size_t)R * H_ + J] = cn;
    h_out[(size_t)R * H_ + J] = f2bf(sigm(ov) * tanhf(cn));
  }
}

// ---- out[b,:] = normalize( h_last[b,:] @ fcW + fcb ); one block per batch row
__global__ __launch_bounds__(256) void final_fc(const short* __restrict__ h,
                                                const float* __restrict__ fcW,
                                                const float* __restrict__ fcb,
                                                float* __restrict__ out) {
  const int b = blockIdx.x, tid = threadIdx.x;
  __shared__ float hrow[512];
  __shared__ float red[256];
  for (int k = tid; k < 512; k += 256) hrow[k] = bf2f(h[b * 512 + k]);
  __syncthreads();
  float a0 = fcb[tid], a1 = fcb[tid + 256];
  for (int k = 0; k < 512; ++k) {
    float hv = hrow[k];
    a0 += hv * fcW[(size_t)k * 512 + tid];
    a1 += hv * fcW[(size_t)k * 512 + tid + 256];
  }
  red[tid] = a0 * a0 + a1 * a1;
  __syncthreads();
  for (int s = 128; s > 0; s >>= 1) {
    if (tid < s) red[tid] += red[tid + s];
    __syncthreads();
  }
  float scale = 1.0f / fmaxf(sqrtf(red[0]), 1e-12f);
  out[(size_t)b * 512 + tid] = a0 * scale;
  out[(size_t)b * 512 + tid + 256] = a1 * scale;
}

extern "C" void kernel_launch(void* const* d_in, const int* in_sizes, int n_in,
                              void* d_out, int out_size, void* d_ws, size_t ws_size,
                              hipStream_t stream) {
  const int*   captions = (const int*)d_in[0];
  const float* emb      = (const float*)d_in[1];
  const float* Wx       = (const float*)d_in[2];
  const float* bx       = (const float*)d_in[3];
  const float* Uh       = (const float*)d_in[4];
  const float* bu       = (const float*)d_in[5];
  const float* fcW      = (const float*)d_in[6];
  const float* fcb      = (const float*)d_in[7];
  float* out = (float*)d_out;

  char* ws = (char*)d_ws;
  size_t off = 0;
  auto alloc = [&](size_t bytes) {
    char* p = ws + off;
    off += (bytes + 255) & ~(size_t)255;
    return p;
  };
  short* Wt   = (short*)alloc((size_t)NG * KK * 2);   // 4 MB
  float* bcat = (float*)alloc((size_t)NG * 4);
  short* hA   = (short*)alloc((size_t)B_ * H_ * 2);
  short* hB   = (short*)alloc((size_t)B_ * H_ * 2);
  float* cbuf = (float*)alloc((size_t)B_ * H_ * 4);
  short* xs   = (short*)alloc((size_t)T_ * B_ * E_ * 2);  // 32 MB
  bool stage = (off <= ws_size);

  hipMemsetAsync(hA, 0, (size_t)B_ * H_ * 2, stream);
  hipMemsetAsync(cbuf, 0, (size_t)B_ * H_ * 4, stream);

  prep_w<<<dim3(16, 32), 256, 0, stream>>>(Wx, Uh, Wt);
  prep_b<<<8, 256, 0, stream>>>(bx, bu, bcat);
  if (stage) stage_x<<<T_ * B_, 256, 0, stream>>>(captions, emb, xs);

  for (int t = 0; t < T_; ++t) {
    const short* hi = (t & 1) ? hB : hA;
    short*       ho = (t & 1) ? hA : hB;
    lstm_step<<<dim3(8, 32), 256, 0, stream>>>(stage ? xs : (const short*)nullptr,
                                               captions, emb, Wt, bcat, hi, ho, cbuf, t);
  }
  // t=127 (odd) wrote into hA
  final_fc<<<B_, 256, 0, stream>>>(hA, fcW, fcb, out);
}